// Round 4
// baseline (257.410 us; speedup 1.0000x reference)
//
#include <hip/hip_runtime.h>

typedef __bf16    bf16x8 __attribute__((ext_vector_type(8)));
typedef __bf16    bf16x4 __attribute__((ext_vector_type(4)));
typedef float     f32x16 __attribute__((ext_vector_type(16)));

#define BM 128
#define BN 128
#define BK 64

// async global->LDS, 16B per lane. LDS dest must be wave-uniform base + lane*16.
__device__ __forceinline__ void gload_lds16(const __bf16* g, __bf16* l) {
  __builtin_amdgcn_global_load_lds(
      (const __attribute__((address_space(1))) void*)g,
      (__attribute__((address_space(3))) void*)l,
      16, 0, 0);
}

// One launch converts x (8192 blocks) + Wq/Wk/Wv (3072 blocks) to bf16.
// Block 0 additionally zero-inits the row-sum accumulator.
__global__ void cvt_all(const float* __restrict__ x, const float* __restrict__ Wq,
                        const float* __restrict__ Wk, const float* __restrict__ Wv,
                        __bf16* __restrict__ xb, __bf16* __restrict__ Wqk,
                        __bf16* __restrict__ Wvb, float* __restrict__ lsum) {
  int b = blockIdx.x;
  if (b == 0) {
    for (int j = threadIdx.x; j < 8192; j += 256) lsum[j] = 0.f;
  }
  const float* src;
  __bf16* dst;
  int i;
  if (b < 8192) {
    src = x; dst = xb; i = b * 256 + threadIdx.x;
  } else {
    b -= 8192;
    const int mat = b >> 10;
    i = (b & 1023) * 256 + threadIdx.x;
    src = (mat == 0) ? Wq : (mat == 1) ? Wk : Wv;
    dst = (mat == 0) ? Wqk : (mat == 1) ? (Wqk + 1048576) : Wvb;
  }
  float4 v = ((const float4*)src)[i];
  bf16x4 o;
  o[0] = (__bf16)v.x; o[1] = (__bf16)v.y; o[2] = (__bf16)v.z; o[3] = (__bf16)v.w;
  ((bf16x4*)dst)[i] = o;
}

// ============================================================================
// 128x128 tile, BK=64, 256 thr = 4 waves (2Mx2N), per-wave 64x64 output.
// ROUND 4: inner math switched 32x mfma_16x16x32 -> 16x mfma_32x32x16 per
// K-step (same FLOPs, half the MFMA instructions, higher measured pipe
// ceiling 2382-2495 vs 2075 TF). Staging + LDS layout + swizzle UNCHANGED
// from the proven structure (R&7 16B-slot XOR; 8-lane read groups cover all
// 8 slots -> conflict-free, SQ_LDS_BANK_CONFLICT=0 measured).
// A-frag (32x32x16): lane holds row=lane&31, k-chunk=(lane>>5)*8 (8 bf16,
// one b128). C/D layout (verified m74/m101): col=lane&31,
// row=(reg&3)+8*(reg>>2)+4*(lane>>5), reg in [0,16).
// MODE 0: QK epilogue  — bias + bf16 store, split by gn>>10 to Q / K
// MODE 1: VT epilogue  — bias0[gm] + bf16 store to Vt[b][gm][s]
// MODE 2: scores       — e = exp(v/32) stored bf16 + per-row sums into lsum
// MODE 3: PV           — fp32 store of acc * (1/lsum[row])
// ============================================================================
template<int MODE>
__global__ __launch_bounds__(256, 2)
void gemm_bt(const __bf16* __restrict__ A, const __bf16* __restrict__ B,
             float* __restrict__ C,
             int lda, int ldb, int ldc, int K,
             long sA, long sB, long sC,
             const float* __restrict__ bias0, const float* __restrict__ bias1,
             float* __restrict__ lsum,
             __bf16* __restrict__ out0, __bf16* __restrict__ out1)
{
  A += (long)blockIdx.z * sA;
  B += (long)blockIdx.z * sB;

  const int tid  = threadIdx.x;
  const int wave = tid >> 6;
  const int lane = tid & 63;
  const int l31  = lane & 31;
  const int lh   = lane >> 5;
  const int bm0  = blockIdx.x * BM;
  const int bn0  = blockIdx.y * BN;
  const int wm   = (wave >> 1) * 64;
  const int wn   = (wave & 1) * 64;

  __shared__ __align__(16) __bf16 As[BM * BK];   // 16 KB
  __shared__ __align__(16) __bf16 Bs[BN * BK];   // 16 KB

  f32x16 acc[2][2];
#pragma unroll
  for (int i = 0; i < 2; ++i)
#pragma unroll
    for (int j = 0; j < 2; ++j)
#pragma unroll
      for (int c = 0; c < 16; ++c)
        acc[i][j][c] = 0.f;

  // Staging: tile 128x64 bf16 = 16 KB = 4 chunks x (256 thr x 16 B).
  // Chunk c, thread tid -> LDS elements [c*2048 + tid*8, +8):
  //   row r = c*32 + (tid>>3), 16B-slot g' = tid&7.
  // Global source applies the swizzle: k-slot g = g' ^ (r&7).
  const __bf16* Ag[4];
  const __bf16* Bg[4];
#pragma unroll
  for (int c = 0; c < 4; ++c) {
    const int r  = c * 32 + (tid >> 3);
    const int g  = (tid & 7) ^ (r & 7);
    Ag[c] = A + (size_t)(bm0 + r) * lda + g * 8;
    Bg[c] = B + (size_t)(bn0 + r) * ldb + g * 8;
  }

  for (int k0 = 0; k0 < K; k0 += BK) {
#pragma unroll
    for (int c = 0; c < 4; ++c) {
      gload_lds16(Ag[c] + k0, &As[c * 2048 + tid * 8]);
      gload_lds16(Bg[c] + k0, &Bs[c * 2048 + tid * 8]);
    }
    __syncthreads();

#pragma unroll
    for (int s = 0; s < 4; ++s) {        // four K=16 steps of BK=64
      const int grp = s * 2 + lh;        // 16B k-slot 0..7
      bf16x8 af[2], bfv[2];
#pragma unroll
      for (int mt = 0; mt < 2; ++mt) {
        const int R = wm + mt * 32 + l31;
        af[mt] = *(const bf16x8*)&As[R * BK + ((grp ^ (R & 7)) * 8)];
      }
#pragma unroll
      for (int nt = 0; nt < 2; ++nt) {
        const int R = wn + nt * 32 + l31;
        bfv[nt] = *(const bf16x8*)&Bs[R * BK + ((grp ^ (R & 7)) * 8)];
      }
#pragma unroll
      for (int mt = 0; mt < 2; ++mt)
#pragma unroll
        for (int nt = 0; nt < 2; ++nt)
          acc[mt][nt] = __builtin_amdgcn_mfma_f32_32x32x16_bf16(
              af[mt], bfv[nt], acc[mt][nt], 0, 0, 0);
    }
    __syncthreads();
  }

  // Epilogue. 32x32 C/D layout: col = l31, row = (j&3)+8*(j>>2)+4*lh.
  if (MODE == 2) {
    // scores: w = exp(v/32) -> bf16; row sums into lsum via shfl+atomic.
    const long zc = (long)blockIdx.z * sC;
#pragma unroll
    for (int mt = 0; mt < 2; ++mt) {
#pragma unroll
      for (int j = 0; j < 16; ++j) {
        const int gm = bm0 + wm + mt * 32 + (j & 3) + 8 * (j >> 2) + 4 * lh;
        float part = 0.f;
#pragma unroll
        for (int nt = 0; nt < 2; ++nt) {
          const int gn = bn0 + wn + nt * 32 + l31;
          const __bf16 eb = (__bf16)__expf(acc[mt][nt][j] * 0.03125f);
          out0[zc + (size_t)gm * ldc + gn] = eb;
          part += (float)eb;  // sum the rounded values PV will actually read
        }
        part += __shfl_xor(part, 1);
        part += __shfl_xor(part, 2);
        part += __shfl_xor(part, 4);
        part += __shfl_xor(part, 8);
        part += __shfl_xor(part, 16);
        if (l31 == 0)
          atomicAdd(&lsum[blockIdx.z * 2048 + gm], part);
      }
    }
  } else if (MODE == 3) {
    // PV: normalize by row sum while storing fp32 (32 lanes x 4B = 128B rows).
    const long zc = (long)blockIdx.z * sC;
#pragma unroll
    for (int mt = 0; mt < 2; ++mt) {
#pragma unroll
      for (int j = 0; j < 16; ++j) {
        const int gm = bm0 + wm + mt * 32 + (j & 3) + 8 * (j >> 2) + 4 * lh;
        const float rv = 1.0f / lsum[blockIdx.z * 2048 + gm];
#pragma unroll
        for (int nt = 0; nt < 2; ++nt) {
          const int gn = bn0 + wn + nt * 32 + l31;
          C[zc + (size_t)gm * ldc + gn] = acc[mt][nt][j] * rv;
        }
      }
    }
  } else if (MODE == 0) {
#pragma unroll
    for (int mt = 0; mt < 2; ++mt) {
#pragma unroll
      for (int nt = 0; nt < 2; ++nt) {
        const int gn  = bn0 + wn + nt * 32 + l31;
        const int mat = gn >> 10;          // uniform per 32-col slice
        const int d   = gn & 1023;
        const float* bias = (mat == 0) ? bias0 : bias1;
        __bf16* dst = (mat == 0) ? out0 : out1;
        const float bv = bias[d];
#pragma unroll
        for (int j = 0; j < 16; ++j) {
          const int gm = bm0 + wm + mt * 32 + (j & 3) + 8 * (j >> 2) + 4 * lh;
          dst[(size_t)gm * 1024 + d] = (__bf16)(acc[mt][nt][j] + bv);
        }
      }
    }
  } else {  // MODE 1 (VT)
#pragma unroll
    for (int mt = 0; mt < 2; ++mt) {
#pragma unroll
      for (int nt = 0; nt < 2; ++nt) {
        const int gn = bn0 + wn + nt * 32 + l31;
        const int b  = gn >> 11, s2 = gn & 2047;
#pragma unroll
        for (int j = 0; j < 16; ++j) {
          const int gm = bm0 + wm + mt * 32 + (j & 3) + 8 * (j >> 2) + 4 * lh;
          out0[(size_t)b * (1024 * 2048) + (size_t)gm * 2048 + s2] =
              (__bf16)(acc[mt][nt][j] + bias0[gm]);
        }
      }
    }
  }
}

extern "C" void kernel_launch(void* const* d_in, const int* in_sizes, int n_in,
                              void* d_out, int out_size, void* d_ws, size_t ws_size,
                              hipStream_t stream) {
  const float* x  = (const float*)d_in[0];
  const float* Wq = (const float*)d_in[1];
  const float* bq = (const float*)d_in[2];
  const float* Wk = (const float*)d_in[3];
  const float* bk = (const float*)d_in[4];
  const float* Wv = (const float*)d_in[5];
  const float* bv = (const float*)d_in[6];
  float* out = (float*)d_out;

  // ws layout:
  //  [0,16M)    Q    bf16 [8192][1024]
  //  [16,32M)   K    bf16 [8192][1024]
  //  [32,48M)   Vt   bf16 [4][1024][2048]
  //  [48,64M)   xb   bf16 (projection phase only)
  //  [64,68M)   Wqk  bf16 [2048][1024] (projection phase only)
  //  [68,70M)   Wvb  bf16 [1024][1024] (projection phase only)
  //  [48,80M)   Sc   bf16 [4][2048][2048] exp-weights (aliases xb/Wqk/Wvb)
  //  [110M,+32K) lsum fp32 [8192] row sums (zeroed by cvt_all block 0)
  char* ws = (char*)d_ws;
  __bf16* Q    = (__bf16*)(ws);
  __bf16* Kb   = (__bf16*)(ws + (16ull << 20));
  __bf16* Vt   = (__bf16*)(ws + (32ull << 20));
  __bf16* xb   = (__bf16*)(ws + (48ull << 20));
  __bf16* Wqk  = (__bf16*)(ws + (64ull << 20));
  __bf16* Wvb  = (__bf16*)(ws + (68ull << 20));
  __bf16* Sc   = (__bf16*)(ws + (48ull << 20));
  float*  lsum = (float*)(ws + (110ull << 20));

  dim3 blk(256);

  // fp32 -> bf16 (+ lsum zero-init), one launch
  cvt_all<<<11264, blk, 0, stream>>>(x, Wq, Wk, Wv, xb, Wqk, Wvb, lsum);

  // QK: [8192,1024] @ [2048,1024]^T -> Q, K (bf16, +bias)
  gemm_bt<0><<<dim3(64, 16, 1), blk, 0, stream>>>(
      xb, Wqk, nullptr, 1024, 1024, 0, 1024,
      0L, 0L, 0L, bq, bk, nullptr, Q, Kb);

  // VT: Wv[1024,1024] @ xb[8192,1024]^T -> Vt[b][d][s] (bf16, +bias[d])
  gemm_bt<1><<<dim3(8, 64, 1), blk, 0, stream>>>(
      Wvb, xb, nullptr, 1024, 1024, 0, 1024,
      0L, 0L, 0L, bv, nullptr, nullptr, Vt, nullptr);

  // scores: per batch Q[2048,1024] @ K[2048,1024]^T -> bf16 exp-weights + lsum
  gemm_bt<2><<<dim3(16, 16, 4), blk, 0, stream>>>(
      Q, Kb, nullptr, 1024, 1024, 2048, 1024,
      2048L * 1024, 2048L * 1024, 2048L * 2048,
      nullptr, nullptr, lsum, Sc, nullptr);

  // PV: per batch Sc[2048,2048](bf16) @ Vt[1024,2048]^T -> out fp32, /lsum
  gemm_bt<3><<<dim3(16, 8, 4), blk, 0, stream>>>(
      Sc, Vt, out, 2048, 2048, 1024, 2048,
      2048L * 2048, 1024L * 2048, 2048L * 1024,
      nullptr, nullptr, lsum, nullptr, nullptr);
}

// Round 5
// 245.006 us; speedup vs baseline: 1.0506x; 1.0506x over previous
//
#include <hip/hip_runtime.h>

typedef __bf16    bf16x8 __attribute__((ext_vector_type(8)));
typedef __bf16    bf16x4 __attribute__((ext_vector_type(4)));
typedef float     f32x4  __attribute__((ext_vector_type(4)));

#define BM 128
#define BN 128
#define BK 64

// async global->LDS, 16B per lane. LDS dest must be wave-uniform base + lane*16.
__device__ __forceinline__ void gload_lds16(const __bf16* g, __bf16* l) {
  __builtin_amdgcn_global_load_lds(
      (const __attribute__((address_space(1))) void*)g,
      (__attribute__((address_space(3))) void*)l,
      16, 0, 0);
}

// One launch converts x (8192 blocks) + Wq/Wk/Wv (3072 blocks) to bf16.
// Block 0 additionally zero-inits the row-sum accumulator.
__global__ void cvt_all(const float* __restrict__ x, const float* __restrict__ Wq,
                        const float* __restrict__ Wk, const float* __restrict__ Wv,
                        __bf16* __restrict__ xb, __bf16* __restrict__ Wqk,
                        __bf16* __restrict__ Wvb, float* __restrict__ lsum) {
  int b = blockIdx.x;
  if (b == 0) {
    for (int j = threadIdx.x; j < 8192; j += 256) lsum[j] = 0.f;
  }
  const float* src;
  __bf16* dst;
  int i;
  if (b < 8192) {
    src = x; dst = xb; i = b * 256 + threadIdx.x;
  } else {
    b -= 8192;
    const int mat = b >> 10;
    i = (b & 1023) * 256 + threadIdx.x;
    src = (mat == 0) ? Wq : (mat == 1) ? Wk : Wv;
    dst = (mat == 0) ? Wqk : (mat == 1) ? (Wqk + 1048576) : Wvb;
  }
  float4 v = ((const float4*)src)[i];
  bf16x4 o;
  o[0] = (__bf16)v.x; o[1] = (__bf16)v.y; o[2] = (__bf16)v.z; o[3] = (__bf16)v.w;
  ((bf16x4*)dst)[i] = o;
}

// ============================================================================
// PROVEN inner structure (round 0; 16x16x32, 0 bank conflicts, ~47us class).
// Round-4 NOTE: the 32x32x16 variant of this exact layout produced 4.19M
// conflict-cycles (4 cyc per ds_read_b128) — mechanism unresolved; do NOT
// switch MFMA shape without re-measuring conflicts.
// LDS tiles: 16B slot g' of row r holds global k-group (g' ^ (r&7)), swizzle
// applied on the GLOBAL SOURCE address (gload_lds dest must stay linear).
// ============================================================================
__device__ __forceinline__ void gemm_core(
    const __bf16* __restrict__ A, const __bf16* __restrict__ B,
    int lda, int ldb, int K, int bm0, int bn0,
    int tid, int wm, int wn, int quad, int l15,
    __bf16* As, __bf16* Bs, f32x4 (&acc)[4][4])
{
  const __bf16* Ag[4];
  const __bf16* Bg[4];
#pragma unroll
  for (int c = 0; c < 4; ++c) {
    const int r  = c * 32 + (tid >> 3);
    const int g  = (tid & 7) ^ (r & 7);
    Ag[c] = A + (size_t)(bm0 + r) * lda + g * 8;
    Bg[c] = B + (size_t)(bn0 + r) * ldb + g * 8;
  }

  for (int k0 = 0; k0 < K; k0 += BK) {
#pragma unroll
    for (int c = 0; c < 4; ++c) {
      gload_lds16(Ag[c] + k0, &As[c * 2048 + tid * 8]);
      gload_lds16(Bg[c] + k0, &Bs[c * 2048 + tid * 8]);
    }
    __syncthreads();

#pragma unroll
    for (int kk = 0; kk < 2; ++kk) {
      bf16x8 af[4], bfv[4];
#pragma unroll
      for (int i = 0; i < 4; ++i) {
        const int R = wm + i * 16 + l15;
        af[i] = *(const bf16x8*)&As[R * BK + (((kk * 4 + quad) ^ (R & 7)) * 8)];
      }
#pragma unroll
      for (int i = 0; i < 4; ++i) {
        const int R = wn + i * 16 + l15;
        bfv[i] = *(const bf16x8*)&Bs[R * BK + (((kk * 4 + quad) ^ (R & 7)) * 8)];
      }
#pragma unroll
      for (int mi = 0; mi < 4; ++mi)
#pragma unroll
        for (int ni = 0; ni < 4; ++ni)
          acc[mi][ni] = __builtin_amdgcn_mfma_f32_16x16x32_bf16(
              af[mi], bfv[ni], acc[mi][ni], 0, 0, 0);
    }
    __syncthreads();
  }
}

// ============================================================================
// ROUND 5: merged projection launch. QK (1024 blocks) and VT (512 blocks) are
// independent (both read only cvt outputs) and share the same K=1024 gemm —
// one 1536-block launch removes an inter-kernel boundary and back-fills VT's
// poorly-packed 2-round tail behind QK's blocks.
//  blocks [0,1024):  QK  — xb[8192,1024] @ Wqk[2048,1024]^T -> Q,K (+bias)
//  blocks [1024,1536): VT — Wvb[1024,1024] @ xb[8192,1024]^T -> Vt (+bias[gm])
// ============================================================================
__global__ __launch_bounds__(256, 2)
void proj_qkv(const __bf16* __restrict__ xb, const __bf16* __restrict__ Wqk,
              const __bf16* __restrict__ Wvb,
              const float* __restrict__ bq, const float* __restrict__ bk,
              const float* __restrict__ bv,
              __bf16* __restrict__ Q, __bf16* __restrict__ Kb,
              __bf16* __restrict__ Vt)
{
  const int bid  = blockIdx.x;
  const int tid  = threadIdx.x;
  const int wave = tid >> 6;
  const int lane = tid & 63;
  const int quad = lane >> 4;
  const int l15  = lane & 15;
  const int wm   = (wave >> 1) * 64;
  const int wn   = (wave & 1) * 64;

  const bool isQK = bid < 1024;
  const __bf16* A;
  const __bf16* B;
  int bm0, bn0;
  if (isQK) {                       // grid 64 (M) x 16 (N)
    A = xb;  B = Wqk;
    bm0 = (bid & 63) * BM;  bn0 = (bid >> 6) * BN;
  } else {                          // grid 8 (M) x 64 (N)
    const int b2 = bid - 1024;
    A = Wvb; B = xb;
    bm0 = (b2 & 7) * BM;    bn0 = (b2 >> 3) * BN;
  }

  __shared__ __align__(16) __bf16 As[BM * BK];   // 16 KB
  __shared__ __align__(16) __bf16 Bs[BN * BK];   // 16 KB

  f32x4 acc[4][4];
#pragma unroll
  for (int i = 0; i < 4; ++i)
#pragma unroll
    for (int j = 0; j < 4; ++j)
      acc[i][j] = (f32x4){0.f, 0.f, 0.f, 0.f};

  gemm_core(A, B, 1024, 1024, 1024, bm0, bn0, tid, wm, wn, quad, l15,
            As, Bs, acc);

  // Epilogue. C/D layout (verified m89/m91): row m = quad*4+r, col n = lane&15.
  if (isQK) {
#pragma unroll
    for (int mi = 0; mi < 4; ++mi) {
#pragma unroll
      for (int ni = 0; ni < 4; ++ni) {
        const int gn  = bn0 + wn + ni * 16 + l15;
        const int mat = gn >> 10;          // uniform per tile
        const int d   = gn & 1023;
        const float* bias = (mat == 0) ? bq : bk;
        __bf16* dst = (mat == 0) ? Q : Kb;
        const float bvv = bias[d];
#pragma unroll
        for (int r = 0; r < 4; ++r) {
          const int gm = bm0 + wm + mi * 16 + quad * 4 + r;
          dst[(size_t)gm * 1024 + d] = (__bf16)(acc[mi][ni][r] + bvv);
        }
      }
    }
  } else {  // VT: out Vt[b][gm][s], gn = b*2048 + s, bias bv[gm]
#pragma unroll
    for (int mi = 0; mi < 4; ++mi) {
#pragma unroll
      for (int ni = 0; ni < 4; ++ni) {
        const int gn = bn0 + wn + ni * 16 + l15;
        const int b  = gn >> 11, s = gn & 2047;
#pragma unroll
        for (int r = 0; r < 4; ++r) {
          const int gm = bm0 + wm + mi * 16 + quad * 4 + r;
          Vt[(size_t)b * (1024 * 2048) + (size_t)gm * 2048 + s] =
              (__bf16)(acc[mi][ni][r] + bv[gm]);
        }
      }
    }
  }
}

// ============================================================================
// scores / PV kernels (proven round-0 structure, 16x16x32, 0 conflicts).
// MODE 2: scores — e = exp(v/32) stored bf16 + per-row sums into lsum
// MODE 3: PV     — fp32 store of acc * (1/lsum[row])
// ============================================================================
template<int MODE>
__global__ __launch_bounds__(256, 2)
void gemm_bt(const __bf16* __restrict__ A, const __bf16* __restrict__ B,
             float* __restrict__ C,
             int lda, int ldb, int ldc, int K,
             long sA, long sB, long sC,
             float* __restrict__ lsum,
             __bf16* __restrict__ out0)
{
  A += (long)blockIdx.z * sA;
  B += (long)blockIdx.z * sB;

  const int tid  = threadIdx.x;
  const int wave = tid >> 6;
  const int lane = tid & 63;
  const int quad = lane >> 4;
  const int l15  = lane & 15;
  const int bm0  = blockIdx.x * BM;
  const int bn0  = blockIdx.y * BN;
  const int wm   = (wave >> 1) * 64;
  const int wn   = (wave & 1) * 64;

  __shared__ __align__(16) __bf16 As[BM * BK];   // 16 KB
  __shared__ __align__(16) __bf16 Bs[BN * BK];   // 16 KB

  f32x4 acc[4][4];
#pragma unroll
  for (int i = 0; i < 4; ++i)
#pragma unroll
    for (int j = 0; j < 4; ++j)
      acc[i][j] = (f32x4){0.f, 0.f, 0.f, 0.f};

  gemm_core(A, B, lda, ldb, K, bm0, bn0, tid, wm, wn, quad, l15,
            As, Bs, acc);

  if (MODE == 2) {
    // scores: w = exp(v/32) -> bf16; row sums into lsum via shfl+atomic.
#pragma unroll
    for (int mi = 0; mi < 4; ++mi) {
#pragma unroll
      for (int r = 0; r < 4; ++r) {
        const int gm = bm0 + wm + mi * 16 + quad * 4 + r;
        float part = 0.f;
#pragma unroll
        for (int ni = 0; ni < 4; ++ni) {
          const int gn = bn0 + wn + ni * 16 + l15;
          const __bf16 eb = (__bf16)__expf(acc[mi][ni][r] * 0.03125f);
          out0[(long)blockIdx.z * sC + (size_t)gm * ldc + gn] = eb;
          part += (float)eb;  // sum the rounded values PV will actually read
        }
        part += __shfl_xor(part, 1);
        part += __shfl_xor(part, 2);
        part += __shfl_xor(part, 4);
        part += __shfl_xor(part, 8);
        if (l15 == 0)
          atomicAdd(&lsum[blockIdx.z * 2048 + gm], part);
      }
    }
  } else {
    // PV: normalize by row sum while storing fp32.
#pragma unroll
    for (int mi = 0; mi < 4; ++mi) {
#pragma unroll
      for (int r = 0; r < 4; ++r) {
        const int gm = bm0 + wm + mi * 16 + quad * 4 + r;
        const float rv = 1.0f / lsum[blockIdx.z * 2048 + gm];
#pragma unroll
        for (int ni = 0; ni < 4; ++ni) {
          const int gn = bn0 + wn + ni * 16 + l15;
          C[(long)blockIdx.z * sC + (size_t)gm * ldc + gn] = acc[mi][ni][r] * rv;
        }
      }
    }
  }
}

extern "C" void kernel_launch(void* const* d_in, const int* in_sizes, int n_in,
                              void* d_out, int out_size, void* d_ws, size_t ws_size,
                              hipStream_t stream) {
  const float* x  = (const float*)d_in[0];
  const float* Wq = (const float*)d_in[1];
  const float* bq = (const float*)d_in[2];
  const float* Wk = (const float*)d_in[3];
  const float* bk = (const float*)d_in[4];
  const float* Wv = (const float*)d_in[5];
  const float* bv = (const float*)d_in[6];
  float* out = (float*)d_out;

  // ws layout:
  //  [0,16M)    Q    bf16 [8192][1024]
  //  [16,32M)   K    bf16 [8192][1024]
  //  [32,48M)   Vt   bf16 [4][1024][2048]
  //  [48,64M)   xb   bf16 (projection phase only)
  //  [64,68M)   Wqk  bf16 [2048][1024] (projection phase only)
  //  [68,70M)   Wvb  bf16 [1024][1024] (projection phase only)
  //  [48,80M)   Sc   bf16 [4][2048][2048] exp-weights (aliases xb/Wqk/Wvb)
  //  [110M,+32K) lsum fp32 [8192] row sums (zeroed by cvt_all block 0)
  char* ws = (char*)d_ws;
  __bf16* Q    = (__bf16*)(ws);
  __bf16* Kb   = (__bf16*)(ws + (16ull << 20));
  __bf16* Vt   = (__bf16*)(ws + (32ull << 20));
  __bf16* xb   = (__bf16*)(ws + (48ull << 20));
  __bf16* Wqk  = (__bf16*)(ws + (64ull << 20));
  __bf16* Wvb  = (__bf16*)(ws + (68ull << 20));
  __bf16* Sc   = (__bf16*)(ws + (48ull << 20));
  float*  lsum = (float*)(ws + (110ull << 20));

  dim3 blk(256);

  // fp32 -> bf16 (+ lsum zero-init), one launch
  cvt_all<<<11264, blk, 0, stream>>>(x, Wq, Wk, Wv, xb, Wqk, Wvb, lsum);

  // Merged QK + VT projection (independent outputs, shared structure)
  proj_qkv<<<1536, blk, 0, stream>>>(xb, Wqk, Wvb, bq, bk, bv, Q, Kb, Vt);

  // scores: per batch Q[2048,1024] @ K[2048,1024]^T -> bf16 exp-weights + lsum
  gemm_bt<2><<<dim3(16, 16, 4), blk, 0, stream>>>(
      Q, Kb, nullptr, 1024, 1024, 2048, 1024,
      2048L * 1024, 2048L * 1024, 2048L * 2048,
      lsum, Sc);

  // PV: per batch Sc[2048,2048](bf16) @ Vt[1024,2048]^T -> out fp32, /lsum
  gemm_bt<3><<<dim3(16, 8, 4), blk, 0, stream>>>(
      Sc, Vt, out, 2048, 2048, 1024, 2048,
      2048L * 2048, 1024L * 2048, 2048L * 1024,
      lsum, nullptr);
}